// Round 7
// baseline (378.052 us; speedup 1.0000x reference)
//
#include <hip/hip_runtime.h>
#include <stdint.h>

typedef unsigned int u32;
typedef unsigned short u16;
typedef u32 u32x4 __attribute__((ext_vector_type(4)));
typedef float f32x4 __attribute__((ext_vector_type(4)));

#define MEM_DIM 256
#define FEA 1000
#define FPAD 1024
#define BM 128          // rows per block (4 waves x 32 rows)
#define NIT 32          // f-iterations of BF=32
#define NOUT 33554432   // 32*64*64*256

// f32 -> bf16 (RNE, valid for finite normals/zero) in pure integer ops
__device__ __forceinline__ u16 f2bf(float x) {
  u32 u = __builtin_bit_cast(u32, x);
  u32 r = (u + 0x7fffu + ((u >> 16) & 1u)) >> 16;
  return (u16)r;
}

__device__ __forceinline__ u32 packbf(float a, float b) {
  return (u32)f2bf(a) | ((u32)f2bf(b) << 16);
}

__device__ __forceinline__ void mfma16(f32x4& acc, u32x4 a, u32x4 b) {
  asm("v_mfma_f32_16x16x32_bf16 %0, %1, %2, %0" : "+v"(acc) : "v"(a), "v"(b));
}

#define GLOAD_LDS16(gp, lp) __builtin_amdgcn_global_load_lds( \
    (const __attribute__((address_space(1))) u32*)(gp),       \
    (__attribute__((address_space(3))) u32*)(lp), 16, 0, 0)

// Wswz[f][c ^ ((f&7)<<3)]  (row-major, 1024x256, rows>=1000 zero) -- LDS-staged
// Wt  [c][f]               (plain transpose, 256x1024) -- read direct from
//   global in GEMM2 (L2-resident, block-invariant addresses)
__global__ void prep_kernel(const float* __restrict__ W, u16* __restrict__ Wswz,
                            u16* __restrict__ Wt, float* __restrict__ entpart) {
  int f = blockIdx.x;   // 0..1023
  int c = threadIdx.x;  // 0..255
  float v = (f < FEA) ? W[f * MEM_DIM + c] : 0.0f;
  u16 b = f2bf(v);
  Wswz[f * MEM_DIM + (c ^ ((f & 7) << 3))] = b;
  Wt[c * FPAD + f] = b;
  if (blockIdx.x < 4) entpart[blockIdx.x * 256 + threadIdx.x] = 0.0f;
}

// Fused flash-style softmax-attention over memory slots.
// LDS = Wb dbuf only (32KB). Wt fragments straight from global (L2-hit).
// launch_bounds kept at the R4-PROVEN (256,2): R5/R6 both failed with
// absmax ~2e-3 and their only shared change was (256,4) -- forcing a
// 128-reg cap on ~220 live regs (spill-heavy codegen around inline-asm
// MFMA) is implicated; this round is the single-variable bisect.
__global__ __launch_bounds__(256, 2) void fused_kernel(
    const float* __restrict__ X, const u16* __restrict__ Wswz,
    const u16* __restrict__ Wt, float* __restrict__ Out,
    float* __restrict__ entpart) {
  // LDS: Wb dbuf [2][32][256]bf16 = 32KB
  __shared__ __attribute__((aligned(16))) char smem[32768];
  __shared__ float entw[4];
  const int tid = threadIdx.x;
  const int wave = tid >> 6;
  const int lane = tid & 63;
  const int g = lane >> 4;   // 0..3
  const int q = lane & 15;   // 0..15
  const long rowbase = (long)blockIdx.x * BM + wave * 32;

  // X fragments: B-operand, lane holds X[m=q][k=8g+e]
  u32x4 xf[2][8];  // [msub][kk]
#pragma unroll
  for (int ms = 0; ms < 2; ++ms) {
    const float* xr = X + (rowbase + ms * 16 + q) * MEM_DIM;
#pragma unroll
    for (int kk = 0; kk < 8; ++kk) {
      const f32x4* p = (const f32x4*)(xr + kk * 32 + g * 8);
      f32x4 a = p[0], b = p[1];
      u32x4 v;
      v.x = packbf(a.x, a.y); v.y = packbf(a.z, a.w);
      v.z = packbf(b.x, b.y); v.w = packbf(b.z, b.w);
      xf[ms][kk] = v;
    }
  }

  const char* WswzB = (const char*)Wswz;
  const char* WtB = (const char*)Wt;
  auto stage = [&](int it, int buf) {
#pragma unroll
    for (int jj = 0; jj < 4; ++jj) {
      int j = wave * 4 + jj;
      GLOAD_LDS16(WswzB + (size_t)it * 16384 + j * 1024 + lane * 16,
                  smem + buf * 16384 + j * 1024);
    }
  };

  f32x4 ot[16][2];  // [ctile][msub]: lane holds Ot[c=16ct+4g+r][m=16ms+q]
  f32x4 z4 = {0.f, 0.f, 0.f, 0.f};
#pragma unroll
  for (int i = 0; i < 16; ++i) { ot[i][0] = z4; ot[i][1] = z4; }
  float zz[2] = {0.f, 0.f}, tt[2] = {0.f, 0.f};

  stage(0, 0);
  asm volatile("s_waitcnt vmcnt(0)" ::: "memory");
  __syncthreads();

  for (int it = 0; it < NIT; ++it) {
    const int cur = it & 1;
    if (it + 1 < NIT) stage(it + 1, cur ^ 1);
    const char* wb = smem + cur * 16384;

    // GEMM1': St[f][m], A=W rows (i=16fs+q, k=32kk+8g+e), B=X
    f32x4 st[2][2];
    st[0][0] = z4; st[0][1] = z4; st[1][0] = z4; st[1][1] = z4;
#pragma unroll
    for (int kk = 0; kk < 8; ++kk) {
#pragma unroll
      for (int fs = 0; fs < 2; ++fs) {
        const int fl = fs * 16 + q;
        const int off = fl * 512 + ((kk * 64 + g * 16) ^ ((fl & 7) << 4));
        u32x4 wfrag = *(const u32x4*)(wb + off);
        mfma16(st[fs][0], wfrag, xf[0][kk]);
        mfma16(st[fs][1], wfrag, xf[1][kk]);
      }
    }

    // softmax partials; lane holds St[f=32it+16fs+4g+r][m=16ms+q]
    const int fbase = it * 32;
    u32 pw[2][2][2];  // packed bf16 pairs: [fs][ms][rows(4g,4g+1)|(4g+2,4g+3)]
#pragma unroll
    for (int fs = 0; fs < 2; ++fs) {
#pragma unroll
      for (int ms = 0; ms < 2; ++ms) {
        float pv[4];
#pragma unroll
        for (int r = 0; r < 4; ++r) {
          float s = st[fs][ms][r];
          int fg = fbase + fs * 16 + g * 4 + r;
          float p = (fg < FEA) ? __expf(s) : 0.0f;
          pv[r] = p;
          zz[ms] += p;
          tt[ms] += p * s;
        }
        pw[fs][ms][0] = packbf(pv[0], pv[1]);
        pw[fs][ms][1] = packbf(pv[2], pv[3]);
      }
    }

    // redistribute P (C-layout) -> B-frag: lane needs P[f=8g+2w+h][m=q]
    u32x4 pfrag[2];
#pragma unroll
    for (int ms = 0; ms < 2; ++ms) {
      u32 wd[4];
#pragma unroll
      for (int w = 0; w < 4; ++w) {
        int src = ((2 * (g & 1) + (w >> 1)) << 4) | q;
        u32 v0 = (u32)__shfl((int)pw[0][ms][w & 1], src, 64);
        u32 v1 = (u32)__shfl((int)pw[1][ms][w & 1], src, 64);
        wd[w] = (g >= 2) ? v1 : v0;
      }
      u32x4 pf; pf.x = wd[0]; pf.y = wd[1]; pf.z = wd[2]; pf.w = wd[3];
      pfrag[ms] = pf;
    }

    // GEMM2': Ot[c][m] += Wt-frag (i=16ct+q, k=f=32it+8g+e) * P-frag
    // Wt frags direct from global (plain layout), batched 4 ct at a time;
    // addresses block-invariant -> L2 hits.
    const char* wtg = WtB + (size_t)it * 64 + (size_t)q * 2048 + g * 16;
#pragma unroll
    for (int cb = 0; cb < 4; ++cb) {
      u32x4 wtf[4];
#pragma unroll
      for (int u = 0; u < 4; ++u)
        wtf[u] = *(const u32x4*)(wtg + (size_t)(cb * 4 + u) * 32768);
#pragma unroll
      for (int u = 0; u < 4; ++u) {
        mfma16(ot[cb * 4 + u][0], wtf[u], pfrag[0]);
        mfma16(ot[cb * 4 + u][1], wtf[u], pfrag[1]);
      }
    }

    asm volatile("s_waitcnt vmcnt(0)" ::: "memory");
    __syncthreads();
  }

  // Z/T full per-row sums: reduce over 4 g-replica lanes (xor 16,32)
#pragma unroll
  for (int ms = 0; ms < 2; ++ms) {
    zz[ms] += __shfl_xor(zz[ms], 16, 64);
    zz[ms] += __shfl_xor(zz[ms], 32, 64);
    tt[ms] += __shfl_xor(tt[ms], 16, 64);
    tt[ms] += __shfl_xor(tt[ms], 32, 64);
  }

  // entropy partial: sum of (ln Z - T/Z) over wave's 32 rows (4x replicated)
  float er = 0.0f;
#pragma unroll
  for (int ms = 0; ms < 2; ++ms) er += __logf(zz[ms]) - tt[ms] / zz[ms];
#pragma unroll
  for (int d = 1; d < 64; d <<= 1) er += __shfl_xor(er, d, 64);
  if (lane == 0) entw[wave] = er * 0.25f;

  // normalize + store O (float4, coalesced: 16 rows x 64B per instr)
#pragma unroll
  for (int ms = 0; ms < 2; ++ms) {
    float rz = 1.0f / zz[ms];
    float* orow = Out + (rowbase + ms * 16 + q) * MEM_DIM;
#pragma unroll
    for (int ct = 0; ct < 16; ++ct) {
      f32x4 v = ot[ct][ms] * rz;
      *(f32x4*)(orow + ct * 16 + g * 4) = v;
    }
  }

  __syncthreads();
  if (tid == 0) entpart[blockIdx.x] = entw[0] + entw[1] + entw[2] + entw[3];
}

// batch b = 32 consecutive block partials; mean over H*W*F = 4096*1000
__global__ void ent_final(const float* __restrict__ entpart,
                          float* __restrict__ entout) {
  int b = blockIdx.x;
  int l = threadIdx.x;
  float v = (l < 32) ? entpart[b * 32 + l] : 0.0f;
#pragma unroll
  for (int d = 1; d < 64; d <<= 1) v += __shfl_xor(v, d, 64);
  if (l == 0) entout[b] = v * (1.0f / 4096000.0f);
}

extern "C" void kernel_launch(void* const* d_in, const int* in_sizes, int n_in,
                              void* d_out, int out_size, void* d_ws, size_t ws_size,
                              hipStream_t stream) {
  (void)in_sizes; (void)n_in; (void)out_size;
  const float* X = (const float*)d_in[0];   // [131072, 256] f32
  const float* W = (const float*)d_in[1];   // [1000, 256] f32
  float* Out = (float*)d_out;               // [131072,256] f32 then [32] ent
  u16* Wswz = (u16*)d_ws;                           // 512 KB
  u16* Wt = (u16*)((char*)d_ws + 524288);           // 512 KB
  float* entpart = (float*)((char*)d_ws + 1048576); // 4 KB
  if (ws_size < 1048576 + 4096) return;
  prep_kernel<<<dim3(1024), dim3(256), 0, stream>>>(W, Wswz, Wt, entpart);
  fused_kernel<<<dim3(1024), dim3(256), 0, stream>>>(X, Wswz, Wt, Out, entpart);
  ent_final<<<dim3(32), dim3(64), 0, stream>>>(entpart, Out + NOUT);
}

// Round 8
// 223.830 us; speedup vs baseline: 1.6890x; 1.6890x over previous
//
#include <hip/hip_runtime.h>
#include <stdint.h>

typedef unsigned int u32;
typedef unsigned short u16;
typedef u32 u32x4 __attribute__((ext_vector_type(4)));
typedef float f32x4 __attribute__((ext_vector_type(4)));

#define MEM_DIM 256
#define FEA 1000
#define FPAD 1024
#define BM 128          // rows per block (4 waves x 32 rows)
#define NIT 32          // f-iterations of BF=32
#define NOUT 33554432   // 32*64*64*256

// f32 -> bf16 (RNE, valid for finite normals/zero) in pure integer ops
__device__ __forceinline__ u16 f2bf(float x) {
  u32 u = __builtin_bit_cast(u32, x);
  u32 r = (u + 0x7fffu + ((u >> 16) & 1u)) >> 16;
  return (u16)r;
}

__device__ __forceinline__ u32 packbf(float a, float b) {
  return (u32)f2bf(a) | ((u32)f2bf(b) << 16);
}

__device__ __forceinline__ void mfma16(f32x4& acc, u32x4 a, u32x4 b) {
  asm("v_mfma_f32_16x16x32_bf16 %0, %1, %2, %0" : "+v"(acc) : "v"(a), "v"(b));
}

#define GLOAD_LDS16(gp, lp) __builtin_amdgcn_global_load_lds( \
    (const __attribute__((address_space(1))) u32*)(gp),       \
    (__attribute__((address_space(3))) u32*)(lp), 16, 0, 0)

// Wswz[f][c ^ ((f&7)<<3)]  (row-major, 1024x256, rows>=1000 zero)
// Wt  [c][f ^ (((c>>1)&3)<<3)]  (transposed, 256x1024, cols>=1000 zero)
__global__ void prep_kernel(const float* __restrict__ W, u16* __restrict__ Wswz,
                            u16* __restrict__ Wt, float* __restrict__ entpart) {
  int f = blockIdx.x;   // 0..1023
  int c = threadIdx.x;  // 0..255
  float v = (f < FEA) ? W[f * MEM_DIM + c] : 0.0f;
  u16 b = f2bf(v);
  Wswz[f * MEM_DIM + (c ^ ((f & 7) << 3))] = b;
  Wt[c * FPAD + (f ^ (((c >> 1) & 3) << 3))] = b;
  if (blockIdx.x < 4) entpart[blockIdx.x * 256 + threadIdx.x] = 0.0f;
}

// Fused flash-style softmax-attention over memory slots.
// R4 structure + sync skeleton, with GEMM1 software-pipelined ONE ITERATION
// AHEAD: per iter = stage(Wb it+2, Wt it+1); softmax(it) [st from last iter];
// GEMM1(it+1); GEMM2(it); vmcnt(0); barrier. softmax no longer stalls on
// fresh MFMA results and GEMM1 fills the shfl->GEMM2 dependency gap.
// Buffer windows verified: Wb[b] tile T readers run in iter T-1 (before the
// barrier preceding the overwriting stage in iter T); Wt[b] tile T readers in
// iter T (stage T+1 targets the other slot). Math identical to R4.
__global__ __launch_bounds__(256, 2) void fused_kernel(
    const float* __restrict__ X, const u16* __restrict__ Wswz,
    const u16* __restrict__ Wt, float* __restrict__ Out,
    float* __restrict__ entpart) {
  // LDS: Wb dbuf [2][32][256]bf16 @0 (2x16KB), Wt dbuf [2][256][32]bf16 @32768
  __shared__ __attribute__((aligned(16))) char smem[65536];
  __shared__ float entw[4];
  const int tid = threadIdx.x;
  const int wave = tid >> 6;
  const int lane = tid & 63;
  const int g = lane >> 4;   // 0..3
  const int q = lane & 15;   // 0..15
  const long rowbase = (long)blockIdx.x * BM + wave * 32;

  // X fragments: B-operand, lane holds X[m=q][k=8g+e]
  u32x4 xf[2][8];  // [msub][kk]
#pragma unroll
  for (int ms = 0; ms < 2; ++ms) {
    const float* xr = X + (rowbase + ms * 16 + q) * MEM_DIM;
#pragma unroll
    for (int kk = 0; kk < 8; ++kk) {
      const f32x4* p = (const f32x4*)(xr + kk * 32 + g * 8);
      f32x4 a = p[0], b = p[1];
      u32x4 v;
      v.x = packbf(a.x, a.y); v.y = packbf(a.z, a.w);
      v.z = packbf(b.x, b.y); v.w = packbf(b.z, b.w);
      xf[ms][kk] = v;
    }
  }

  const char* WswzB = (const char*)Wswz;
  const char* WtB = (const char*)Wt;
  auto stage_wb = [&](int T, int b) {
#pragma unroll
    for (int jj = 0; jj < 4; ++jj) {
      int j = wave * 4 + jj;
      GLOAD_LDS16(WswzB + (size_t)T * 16384 + j * 1024 + lane * 16,
                  smem + b * 16384 + j * 1024);
    }
  };
  auto stage_wt = [&](int T, int b) {
#pragma unroll
    for (int jj = 0; jj < 4; ++jj) {
      int j = wave * 4 + jj;
      GLOAD_LDS16(WtB + (size_t)T * 64 + (size_t)(16 * j + (lane >> 2)) * 2048
                      + (lane & 3) * 16,
                  smem + 32768 + b * 16384 + j * 1024);
    }
  };

  f32x4 ot[16][2];  // [ctile][msub]: lane holds Ot[c=16ct+4g+r][m=16ms+q]
  f32x4 z4 = {0.f, 0.f, 0.f, 0.f};
#pragma unroll
  for (int i = 0; i < 16; ++i) { ot[i][0] = z4; ot[i][1] = z4; }
  float zz[2] = {0.f, 0.f}, tt[2] = {0.f, 0.f};
  f32x4 st[2][2];   // GEMM1 output, lives across iterations
  u32x4 pfrag[2];

  // GEMM1 for tile whose Wb sits in buffer b -> st
  auto gemm1 = [&](int b) {
    const char* wb = smem + b * 16384;
    st[0][0] = z4; st[0][1] = z4; st[1][0] = z4; st[1][1] = z4;
#pragma unroll
    for (int kk = 0; kk < 8; ++kk) {
#pragma unroll
      for (int fs = 0; fs < 2; ++fs) {
        const int fl = fs * 16 + q;
        const int off = fl * 512 + ((kk * 64 + g * 16) ^ ((fl & 7) << 4));
        u32x4 wfrag = *(const u32x4*)(wb + off);
        mfma16(st[fs][0], wfrag, xf[0][kk]);
        mfma16(st[fs][1], wfrag, xf[1][kk]);
      }
    }
  };

  // softmax partials for tile it (consumes st), builds pfrag via shfl
  auto softmax = [&](int it) {
    const int fbase = it * 32;
    u32 pw[2][2][2];
#pragma unroll
    for (int fs = 0; fs < 2; ++fs) {
#pragma unroll
      for (int ms = 0; ms < 2; ++ms) {
        float pv[4];
#pragma unroll
        for (int r = 0; r < 4; ++r) {
          float s = st[fs][ms][r];
          int fg = fbase + fs * 16 + g * 4 + r;
          float p = (fg < FEA) ? __expf(s) : 0.0f;
          pv[r] = p;
          zz[ms] += p;
          tt[ms] += p * s;
        }
        pw[fs][ms][0] = packbf(pv[0], pv[1]);
        pw[fs][ms][1] = packbf(pv[2], pv[3]);
      }
    }
    // redistribute P (C-layout) -> B-frag: lane needs P[f=8g+2w+h][m=q]
#pragma unroll
    for (int ms = 0; ms < 2; ++ms) {
      u32 wd[4];
#pragma unroll
      for (int w = 0; w < 4; ++w) {
        int src = ((2 * (g & 1) + (w >> 1)) << 4) | q;
        u32 v0 = (u32)__shfl((int)pw[0][ms][w & 1], src, 64);
        u32 v1 = (u32)__shfl((int)pw[1][ms][w & 1], src, 64);
        wd[w] = (g >= 2) ? v1 : v0;
      }
      u32x4 pf; pf.x = wd[0]; pf.y = wd[1]; pf.z = wd[2]; pf.w = wd[3];
      pfrag[ms] = pf;
    }
  };

  // GEMM2 for tile it (Wt in buffer it&1), consumes pfrag
  auto gemm2 = [&](int it) {
    const char* wt = smem + 32768 + (it & 1) * 16384;
#pragma unroll
    for (int ct = 0; ct < 16; ++ct) {
      const int off = ct * 1024 + q * 64 + ((g << 4) ^ (((q >> 1) & 3) << 4));
      u32x4 wtfrag = *(const u32x4*)(wt + off);
      mfma16(ot[ct][0], wtfrag, pfrag[0]);
      mfma16(ot[ct][1], wtfrag, pfrag[1]);
    }
  };

  // Prologue: Wb(0)@b0, Wt(0)@w0, Wb(1)@b1; drain; GEMM1(0); barrier
  stage_wb(0, 0);
  stage_wt(0, 0);
  stage_wb(1, 1);
  asm volatile("s_waitcnt vmcnt(0)" ::: "memory");
  __syncthreads();
  gemm1(0);
  __syncthreads();   // protect b0 from iter-0's stage of Wb(2)

  for (int it = 0; it < NIT - 1; ++it) {
    if (it + 2 < NIT) stage_wb(it + 2, it & 1);
    stage_wt(it + 1, (it + 1) & 1);
    softmax(it);
    gemm1((it + 1) & 1);
    gemm2(it);
    asm volatile("s_waitcnt vmcnt(0)" ::: "memory");
    __syncthreads();
  }
  // Peeled last iteration: no stage, no GEMM1
  softmax(NIT - 1);
  gemm2(NIT - 1);

  // Z/T full per-row sums: reduce over 4 g-replica lanes (xor 16,32)
#pragma unroll
  for (int ms = 0; ms < 2; ++ms) {
    zz[ms] += __shfl_xor(zz[ms], 16, 64);
    zz[ms] += __shfl_xor(zz[ms], 32, 64);
    tt[ms] += __shfl_xor(tt[ms], 16, 64);
    tt[ms] += __shfl_xor(tt[ms], 32, 64);
  }

  // entropy partial: sum of (ln Z - T/Z) over wave's 32 rows (4x replicated)
  float er = 0.0f;
#pragma unroll
  for (int ms = 0; ms < 2; ++ms) er += __logf(zz[ms]) - tt[ms] / zz[ms];
#pragma unroll
  for (int d = 1; d < 64; d <<= 1) er += __shfl_xor(er, d, 64);
  if (lane == 0) entw[wave] = er * 0.25f;

  // normalize + store O (float4, coalesced: 16 rows x 64B per instr)
#pragma unroll
  for (int ms = 0; ms < 2; ++ms) {
    float rz = 1.0f / zz[ms];
    float* orow = Out + (rowbase + ms * 16 + q) * MEM_DIM;
#pragma unroll
    for (int ct = 0; ct < 16; ++ct) {
      f32x4 v = ot[ct][ms] * rz;
      *(f32x4*)(orow + ct * 16 + g * 4) = v;
    }
  }

  __syncthreads();
  if (tid == 0) entpart[blockIdx.x] = entw[0] + entw[1] + entw[2] + entw[3];
}

// batch b = 32 consecutive block partials; mean over H*W*F = 4096*1000
__global__ void ent_final(const float* __restrict__ entpart,
                          float* __restrict__ entout) {
  int b = blockIdx.x;
  int l = threadIdx.x;
  float v = (l < 32) ? entpart[b * 32 + l] : 0.0f;
#pragma unroll
  for (int d = 1; d < 64; d <<= 1) v += __shfl_xor(v, d, 64);
  if (l == 0) entout[b] = v * (1.0f / 4096000.0f);
}

extern "C" void kernel_launch(void* const* d_in, const int* in_sizes, int n_in,
                              void* d_out, int out_size, void* d_ws, size_t ws_size,
                              hipStream_t stream) {
  (void)in_sizes; (void)n_in; (void)out_size;
  const float* X = (const float*)d_in[0];   // [131072, 256] f32
  const float* W = (const float*)d_in[1];   // [1000, 256] f32
  float* Out = (float*)d_out;               // [131072,256] f32 then [32] ent
  u16* Wswz = (u16*)d_ws;                           // 512 KB
  u16* Wt = (u16*)((char*)d_ws + 524288);           // 512 KB
  float* entpart = (float*)((char*)d_ws + 1048576); // 4 KB
  if (ws_size < 1048576 + 4096) return;
  prep_kernel<<<dim3(1024), dim3(256), 0, stream>>>(W, Wswz, Wt, entpart);
  fused_kernel<<<dim3(1024), dim3(256), 0, stream>>>(X, Wswz, Wt, Out, entpart);
  ent_final<<<dim3(32), dim3(64), 0, stream>>>(entpart, Out + NOUT);
}

// Round 9
// 186.378 us; speedup vs baseline: 2.0284x; 1.2009x over previous
//
#include <hip/hip_runtime.h>
#include <stdint.h>

typedef unsigned int u32;
typedef unsigned short u16;
typedef u32 u32x4 __attribute__((ext_vector_type(4)));
typedef float f32x4 __attribute__((ext_vector_type(4)));

#define MEM_DIM 256
#define FEA 1000
#define FPAD 1024
#define BM 128          // rows per block (4 waves x 32 rows)
#define NIT 32          // f-iterations of BF=32
#define NOUT 33554432   // 32*64*64*256

// f32 -> bf16 (RNE) integer version -- prep kernel only
__device__ __forceinline__ u16 f2bf(float x) {
  u32 u = __builtin_bit_cast(u32, x);
  u32 r = (u + 0x7fffu + ((u >> 16) & 1u)) >> 16;
  return (u16)r;
}

// pack two f32 -> u32 of 2 bf16 (RNE) in ONE VALU op (T12): lo=first arg.
// Replaces ~11-op integer packbf; bit-identical rounding for normals.
__device__ __forceinline__ u32 cvtpk(float lo, float hi) {
  u32 d;
  asm("v_cvt_pk_bf16_f32 %0, %1, %2" : "=v"(d) : "v"(lo), "v"(hi));
  return d;
}

__device__ __forceinline__ void mfma16(f32x4& acc, u32x4 a, u32x4 b) {
  asm("v_mfma_f32_16x16x32_bf16 %0, %1, %2, %0" : "+v"(acc) : "v"(a), "v"(b));
}

#define GLOAD_LDS16(gp, lp) __builtin_amdgcn_global_load_lds( \
    (const __attribute__((address_space(1))) u32*)(gp),       \
    (__attribute__((address_space(3))) u32*)(lp), 16, 0, 0)

// Wswz[f][c ^ ((f&7)<<3)]  (row-major, 1024x256, rows>=1000 zero)
// Wt  [c][f ^ (((c>>1)&3)<<3)]  (transposed, 256x1024, cols>=1000 zero)
__global__ void prep_kernel(const float* __restrict__ W, u16* __restrict__ Wswz,
                            u16* __restrict__ Wt, float* __restrict__ entpart) {
  int f = blockIdx.x;   // 0..1023
  int c = threadIdx.x;  // 0..255
  float v = (f < FEA) ? W[f * MEM_DIM + c] : 0.0f;
  u16 b = f2bf(v);
  Wswz[f * MEM_DIM + (c ^ ((f & 7) << 3))] = b;
  Wt[c * FPAD + (f ^ (((c >> 1) & 3) << 3))] = b;
  if (blockIdx.x < 4) entpart[blockIdx.x * 256 + threadIdx.x] = 0.0f;
}

// Fused flash-style softmax-attention over memory slots. R4 skeleton
// (proven: dbuf Wb+Wt, 1 vmcnt(0)+barrier per iter, shfl P-redistribution)
// with a VALU diet: v_cvt_pk_bf16_f32 packing, no per-element pad mask
// (pad W rows are exact zeros -> S=0 -> p=1 -> contributes +1 to Z only;
// Z -= 24 after the reduce is exact), quad-partial Z/T accumulation.
__global__ __launch_bounds__(256, 2) void fused_kernel(
    const float* __restrict__ X, const u16* __restrict__ Wswz,
    const u16* __restrict__ Wt, float* __restrict__ Out,
    float* __restrict__ entpart) {
  // LDS: Wb dbuf [2][32][256]bf16 @0 (2x16KB), Wt dbuf [2][256][32]bf16 @32768
  __shared__ __attribute__((aligned(16))) char smem[65536];
  __shared__ float entw[4];
  const int tid = threadIdx.x;
  const int wave = tid >> 6;
  const int lane = tid & 63;
  const int g = lane >> 4;   // 0..3
  const int q = lane & 15;   // 0..15
  const long rowbase = (long)blockIdx.x * BM + wave * 32;

  // X fragments: B-operand, lane holds X[m=q][k=8g+e]
  u32x4 xf[2][8];  // [msub][kk]
#pragma unroll
  for (int ms = 0; ms < 2; ++ms) {
    const float* xr = X + (rowbase + ms * 16 + q) * MEM_DIM;
#pragma unroll
    for (int kk = 0; kk < 8; ++kk) {
      const f32x4* p = (const f32x4*)(xr + kk * 32 + g * 8);
      f32x4 a = p[0], b = p[1];
      u32x4 v;
      v.x = cvtpk(a.x, a.y); v.y = cvtpk(a.z, a.w);
      v.z = cvtpk(b.x, b.y); v.w = cvtpk(b.z, b.w);
      xf[ms][kk] = v;
    }
  }

  const char* WswzB = (const char*)Wswz;
  const char* WtB = (const char*)Wt;
  auto stage = [&](int it, int buf) {
#pragma unroll
    for (int jj = 0; jj < 4; ++jj) {
      int j = wave * 4 + jj;
      GLOAD_LDS16(WswzB + (size_t)it * 16384 + j * 1024 + lane * 16,
                  smem + buf * 16384 + j * 1024);
    }
#pragma unroll
    for (int jj = 0; jj < 4; ++jj) {
      int j = wave * 4 + jj;
      GLOAD_LDS16(WtB + (size_t)it * 64 + (size_t)(16 * j + (lane >> 2)) * 2048
                      + (lane & 3) * 16,
                  smem + 32768 + buf * 16384 + j * 1024);
    }
  };

  f32x4 ot[16][2];  // [ctile][msub]: lane holds Ot[c=16ct+4g+r][m=16ms+q]
  f32x4 z4 = {0.f, 0.f, 0.f, 0.f};
#pragma unroll
  for (int i = 0; i < 16; ++i) { ot[i][0] = z4; ot[i][1] = z4; }
  float zz[2] = {0.f, 0.f}, tt[2] = {0.f, 0.f};

  stage(0, 0);
  asm volatile("s_waitcnt vmcnt(0)" ::: "memory");
  __syncthreads();

  for (int it = 0; it < NIT; ++it) {
    const int cur = it & 1;
    if (it + 1 < NIT) stage(it + 1, cur ^ 1);
    const char* wb = smem + cur * 16384;
    const char* wt = smem + 32768 + cur * 16384;

    // GEMM1': St[f][m], A=W rows (i=16fs+q, k=32kk+8g+e), B=X
    f32x4 st[2][2];
    st[0][0] = z4; st[0][1] = z4; st[1][0] = z4; st[1][1] = z4;
#pragma unroll
    for (int kk = 0; kk < 8; ++kk) {
#pragma unroll
      for (int fs = 0; fs < 2; ++fs) {
        const int fl = fs * 16 + q;
        const int off = fl * 512 + ((kk * 64 + g * 16) ^ ((fl & 7) << 4));
        u32x4 wfrag = *(const u32x4*)(wb + off);
        mfma16(st[fs][0], wfrag, xf[0][kk]);
        mfma16(st[fs][1], wfrag, xf[1][kk]);
      }
    }

    // softmax partials; lane holds St[f=32it+16fs+4g+r][m=16ms+q]
    // pads (it=31, f>=1000): W rows zero -> s=0 -> p=1; fixed by Z-=24 later.
    u32 pw[2][2][2];  // packed bf16 pairs: [fs][ms][rows(4g,4g+1)|(4g+2,4g+3)]
#pragma unroll
    for (int fs = 0; fs < 2; ++fs) {
#pragma unroll
      for (int ms = 0; ms < 2; ++ms) {
        float s0 = st[fs][ms][0], s1 = st[fs][ms][1];
        float s2 = st[fs][ms][2], s3 = st[fs][ms][3];
        float p0 = __expf(s0), p1 = __expf(s1);
        float p2 = __expf(s2), p3 = __expf(s3);
        zz[ms] += (p0 + p1) + (p2 + p3);
        tt[ms] += (p0 * s0 + p1 * s1) + (p2 * s2 + p3 * s3);
        pw[fs][ms][0] = cvtpk(p0, p1);
        pw[fs][ms][1] = cvtpk(p2, p3);
      }
    }

    // redistribute P (C-layout) -> B-frag: lane needs P[f=8g+2w+h][m=q]
    u32x4 pfrag[2];
#pragma unroll
    for (int ms = 0; ms < 2; ++ms) {
      u32 wd[4];
#pragma unroll
      for (int w = 0; w < 4; ++w) {
        int src = ((2 * (g & 1) + (w >> 1)) << 4) | q;
        u32 v0 = (u32)__shfl((int)pw[0][ms][w & 1], src, 64);
        u32 v1 = (u32)__shfl((int)pw[1][ms][w & 1], src, 64);
        wd[w] = (g >= 2) ? v1 : v0;
      }
      u32x4 pf; pf.x = wd[0]; pf.y = wd[1]; pf.z = wd[2]; pf.w = wd[3];
      pfrag[ms] = pf;
    }

    // GEMM2': Ot[c][m] += Wt-frag (i=16ct+q, k=f) * P-frag
#pragma unroll
    for (int ct = 0; ct < 16; ++ct) {
      const int off = ct * 1024 + q * 64 + ((g << 4) ^ (((q >> 1) & 3) << 4));
      u32x4 wtfrag = *(const u32x4*)(wt + off);
      mfma16(ot[ct][0], wtfrag, pfrag[0]);
      mfma16(ot[ct][1], wtfrag, pfrag[1]);
    }

    asm volatile("s_waitcnt vmcnt(0)" ::: "memory");
    __syncthreads();
  }

  // Z/T full per-row sums: reduce over 4 g-replica lanes (xor 16,32),
  // then remove the 24 pad units (exp(0)=1 each) from Z. Exact: pad W rows
  // are true zeros so S(pad)==0 bit-exact.
#pragma unroll
  for (int ms = 0; ms < 2; ++ms) {
    zz[ms] += __shfl_xor(zz[ms], 16, 64);
    zz[ms] += __shfl_xor(zz[ms], 32, 64);
    tt[ms] += __shfl_xor(tt[ms], 16, 64);
    tt[ms] += __shfl_xor(tt[ms], 32, 64);
    zz[ms] -= 24.0f;
  }

  // entropy partial: sum of (ln Z - T/Z) over wave's 32 rows (4x replicated)
  float er = 0.0f;
#pragma unroll
  for (int ms = 0; ms < 2; ++ms) er += __logf(zz[ms]) - tt[ms] / zz[ms];
#pragma unroll
  for (int d = 1; d < 64; d <<= 1) er += __shfl_xor(er, d, 64);
  if (lane == 0) entw[wave] = er * 0.25f;

  // normalize + store O (float4, coalesced: 16 rows x 64B per instr)
#pragma unroll
  for (int ms = 0; ms < 2; ++ms) {
    float rz = 1.0f / zz[ms];
    float* orow = Out + (rowbase + ms * 16 + q) * MEM_DIM;
#pragma unroll
    for (int ct = 0; ct < 16; ++ct) {
      f32x4 v = ot[ct][ms] * rz;
      *(f32x4*)(orow + ct * 16 + g * 4) = v;
    }
  }

  __syncthreads();
  if (tid == 0) entpart[blockIdx.x] = entw[0] + entw[1] + entw[2] + entw[3];
}

// batch b = 32 consecutive block partials; mean over H*W*F = 4096*1000
__global__ void ent_final(const float* __restrict__ entpart,
                          float* __restrict__ entout) {
  int b = blockIdx.x;
  int l = threadIdx.x;
  float v = (l < 32) ? entpart[b * 32 + l] : 0.0f;
#pragma unroll
  for (int d = 1; d < 64; d <<= 1) v += __shfl_xor(v, d, 64);
  if (l == 0) entout[b] = v * (1.0f / 4096000.0f);
}

extern "C" void kernel_launch(void* const* d_in, const int* in_sizes, int n_in,
                              void* d_out, int out_size, void* d_ws, size_t ws_size,
                              hipStream_t stream) {
  (void)in_sizes; (void)n_in; (void)out_size;
  const float* X = (const float*)d_in[0];   // [131072, 256] f32
  const float* W = (const float*)d_in[1];   // [1000, 256] f32
  float* Out = (float*)d_out;               // [131072,256] f32 then [32] ent
  u16* Wswz = (u16*)d_ws;                           // 512 KB
  u16* Wt = (u16*)((char*)d_ws + 524288);           // 512 KB
  float* entpart = (float*)((char*)d_ws + 1048576); // 4 KB
  if (ws_size < 1048576 + 4096) return;
  prep_kernel<<<dim3(1024), dim3(256), 0, stream>>>(W, Wswz, Wt, entpart);
  fused_kernel<<<dim3(1024), dim3(256), 0, stream>>>(X, Wswz, Wt, Out, entpart);
  ent_final<<<dim3(32), dim3(64), 0, stream>>>(entpart, Out + NOUT);
}